// Round 1
// baseline (833.350 us; speedup 1.0000x reference)
//
#include <hip/hip_runtime.h>

// DRR ray-casting for MI355X.
// Geometry constants from the reference.
#define IMG_H 256
#define IMG_W 256
static __device__ __constant__ float kPX     = 1.6875f;
static __device__ __constant__ float kPIERCE = 216.0f;
static __device__ __constant__ float kSAD    = 742.5f;
static __device__ __constant__ float kDAD    = 517.15f;

// mm layout: mm[2*b] = min bits, mm[2*b+1] = max bits (raw values >= 0, so
// float bit pattern ordering == float ordering for unsigned compare).
__global__ void drr_init_mm(unsigned* mm) {
    int i = threadIdx.x;
    if (i < 4) mm[i] = (i & 1) ? 0u : 0x7F800000u;  // max<-0, min<-+inf
}

__global__ __launch_bounds__(256) void drr_main(const float* __restrict__ vol,
                                                const float* __restrict__ batch,
                                                float* __restrict__ raw,
                                                unsigned* __restrict__ mm) {
    const int gid = blockIdx.x * 256 + threadIdx.x;
    const int b   = gid >> 16;          // 65536 pixels per batch image
    const int pix = gid & 0xFFFF;
    const int v   = pix >> 8;
    const int u   = pix & 255;

    // Pose parameters (uniform per batch; 6 scalar loads, L1-cached).
    const float a  = batch[b * 6 + 0];
    const float be = batch[b * 6 + 1];
    const float g  = batch[b * 6 + 2];
    const float tx = batch[b * 6 + 3];
    const float ty = batch[b * 6 + 4];
    const float tz = batch[b * 6 + 5];

    float sa, ca, sb, cb, sg, cg;
    sincosf(a, &sa, &ca);
    sincosf(be, &sb, &cb);
    sincosf(g, &sg, &cg);

    // R = Rz(a) @ Ry(b) @ Rx(g)
    const float R00 = ca * cb;
    const float R01 = ca * sb * sg - sa * cg;
    const float R02 = sa * sg + ca * sb * cg;
    const float R10 = sa * cb;
    const float R11 = ca * cg + sa * sb * sg;
    const float R12 = sa * sb * cg - ca * sg;
    const float R20 = -sb;
    const float R21 = cb * sg;
    const float R22 = cb * cg;

    const float isox = 128.0f + tx, isoy = 128.0f + ty, isoz = 128.0f + tz;
    const float srcx = isox + kSAD * R02;
    const float srcy = isoy + kSAD * R12;
    const float srcz = isoz + kSAD * R22;
    const float dcx  = isox - kDAD * R02;
    const float dcy  = isoy - kDAD * R12;
    const float dcz  = isoz - kDAD * R22;

    const float uu = u * kPX - kPIERCE;
    const float vv = v * kPX - kPIERCE;

    // target = det_c + uu*u_ax + vv*v_ax ; u_ax = R[:,0], v_ax = R[:,1]
    const float tgx = dcx + uu * R00 + vv * R01;
    const float tgy = dcy + uu * R10 + vv * R11;
    const float tgz = dcz + uu * R20 + vv * R21;

    const float rx = tgx - srcx;
    const float ry = tgy - srcy;
    const float rz = tgz - srcz;
    const float length = sqrtf(rx * rx + ry * ry + rz * rz);

    float sum = 0.0f;
    const float tstep = 1.0f / 255.0f;  // t = linspace(0,1,256)
    #pragma unroll 4
    for (int k = 0; k < 256; ++k) {
        const float t  = (float)k * tstep;
        const float px = fmaf(t, rx, srcx);
        const float py = fmaf(t, ry, srcy);
        const float pz = fmaf(t, rz, srcz);

        const float fx = floorf(px), fy = floorf(py), fz = floorf(pz);
        const int ix = (int)fx, iy = (int)fy, iz = (int)fz;
        const float wx = px - fx, wy = py - fy, wz = pz - fz;

        // mode='constant' masks folded into weights; addresses wrapped &255
        // so every load is in-bounds and unconditional (no divergence).
        const float mx0 = ((unsigned)ix       < 256u) ? 1.0f : 0.0f;
        const float mx1 = ((unsigned)(ix + 1) < 256u) ? 1.0f : 0.0f;
        const float my0 = ((unsigned)iy       < 256u) ? 1.0f : 0.0f;
        const float my1 = ((unsigned)(iy + 1) < 256u) ? 1.0f : 0.0f;
        const float mz0 = ((unsigned)iz       < 256u) ? 1.0f : 0.0f;
        const float mz1 = ((unsigned)(iz + 1) < 256u) ? 1.0f : 0.0f;

        const float wx0 = (1.0f - wx) * mx0, wx1 = wx * mx1;
        const float wy0 = (1.0f - wy) * my0, wy1 = wy * my1;
        const float wz0 = (1.0f - wz) * mz0, wz1 = wz * mz1;

        const unsigned bx0 = ((unsigned)ix & 255u) << 16;
        const unsigned bx1 = ((unsigned)(ix + 1) & 255u) << 16;
        const unsigned by0 = ((unsigned)iy & 255u) << 8;
        const unsigned by1 = ((unsigned)(iy + 1) & 255u) << 8;
        const unsigned bz0 = (unsigned)iz & 255u;
        const unsigned bz1 = (unsigned)(iz + 1) & 255u;

        const float v000 = vol[bx0 | by0 | bz0];
        const float v001 = vol[bx0 | by0 | bz1];
        const float v010 = vol[bx0 | by1 | bz0];
        const float v011 = vol[bx0 | by1 | bz1];
        const float v100 = vol[bx1 | by0 | bz0];
        const float v101 = vol[bx1 | by0 | bz1];
        const float v110 = vol[bx1 | by1 | bz0];
        const float v111 = vol[bx1 | by1 | bz1];

        const float c00 = v000 * wz0 + v001 * wz1;
        const float c01 = v010 * wz0 + v011 * wz1;
        const float c10 = v100 * wz0 + v101 * wz1;
        const float c11 = v110 * wz0 + v111 * wz1;
        const float c0  = c00 * wy0 + c01 * wy1;
        const float c1  = c10 * wy0 + c11 * wy1;
        sum += c0 * wx0 + c1 * wx1;
    }

    const float rawv = sum * (length * (1.0f / 256.0f));
    raw[gid] = rawv;

    // Wave64 min/max reduce, one atomic pair per wave (b is uniform per block:
    // 256 blocks per batch image).
    float mn = rawv, mx = rawv;
    #pragma unroll
    for (int off = 32; off >= 1; off >>= 1) {
        mn = fminf(mn, __shfl_xor(mn, off));
        mx = fmaxf(mx, __shfl_xor(mx, off));
    }
    if ((threadIdx.x & 63) == 0) {
        atomicMin(&mm[2 * b + 0], __float_as_uint(mn));
        atomicMax(&mm[2 * b + 1], __float_as_uint(mx));
    }
}

__global__ __launch_bounds__(256) void drr_norm(float* __restrict__ img,
                                                const unsigned* __restrict__ mm) {
    const int gid = blockIdx.x * 256 + threadIdx.x;
    const int b   = gid >> 16;
    const float mn  = __uint_as_float(mm[2 * b + 0]);
    const float mx  = __uint_as_float(mm[2 * b + 1]);
    const float inv = 1.0f / (mx - mn);
    img[gid] = 1.0f - (img[gid] - mn) * inv;
}

extern "C" void kernel_launch(void* const* d_in, const int* in_sizes, int n_in,
                              void* d_out, int out_size, void* d_ws, size_t ws_size,
                              hipStream_t stream) {
    const float* vol   = (const float*)d_in[0];
    const float* batch = (const float*)d_in[1];
    float* out         = (float*)d_out;        // raw staged here, normalized in place
    unsigned* mm       = (unsigned*)d_ws;      // 16 bytes used

    drr_init_mm<<<1, 64, 0, stream>>>(mm);
    drr_main<<<512, 256, 0, stream>>>(vol, batch, out, mm);
    drr_norm<<<512, 256, 0, stream>>>(out, mm);
}

// Round 2
// 556.184 us; speedup vs baseline: 1.4983x; 1.4983x over previous
//
#include <hip/hip_runtime.h>

// DRR ray-casting for MI355X — round 2.
// r1 was latency-bound: Occupancy 21% (grid-limited), VGPR=16 (no MLP).
// r2: 4 waves/ray-segment split (32 waves/CU), 8x8 pixel tiles per wave,
//     2x unrolled sample loop with independent accumulators.

static __device__ __constant__ float kPX     = 1.6875f;
static __device__ __constant__ float kPIERCE = 216.0f;
static __device__ __constant__ float kSAD    = 742.5f;
static __device__ __constant__ float kDAD    = 517.15f;

// mm layout: mm[2*b] = min bits, mm[2*b+1] = max bits (raw values >= 0 so
// float bit pattern ordering == unsigned ordering).
__global__ void drr_init_mm(unsigned* mm) {
    int i = threadIdx.x;
    if (i < 4) mm[i] = (i & 1) ? 0u : 0x7F800000u;  // max<-0, min<-+inf
}

// One trilinear sample at parameter t along the ray.
__device__ __forceinline__ float tri_sample(const float* __restrict__ vol,
                                            float srcx, float srcy, float srcz,
                                            float rx, float ry, float rz, float t) {
    const float px = fmaf(t, rx, srcx);
    const float py = fmaf(t, ry, srcy);
    const float pz = fmaf(t, rz, srcz);

    const float fx = floorf(px), fy = floorf(py), fz = floorf(pz);
    const int ix = (int)fx, iy = (int)fy, iz = (int)fz;
    const float wx = px - fx, wy = py - fy, wz = pz - fz;

    // mode='constant' folded into weights; addresses wrapped &255 so loads
    // are unconditional and in-bounds (no divergence).
    const float mx0 = ((unsigned)ix       < 256u) ? 1.0f : 0.0f;
    const float mx1 = ((unsigned)(ix + 1) < 256u) ? 1.0f : 0.0f;
    const float my0 = ((unsigned)iy       < 256u) ? 1.0f : 0.0f;
    const float my1 = ((unsigned)(iy + 1) < 256u) ? 1.0f : 0.0f;
    const float mz0 = ((unsigned)iz       < 256u) ? 1.0f : 0.0f;
    const float mz1 = ((unsigned)(iz + 1) < 256u) ? 1.0f : 0.0f;

    const unsigned bx0 = ((unsigned)ix & 255u) << 16;
    const unsigned bx1 = ((unsigned)(ix + 1) & 255u) << 16;
    const unsigned by0 = ((unsigned)iy & 255u) << 8;
    const unsigned by1 = ((unsigned)(iy + 1) & 255u) << 8;
    const unsigned bz0 = (unsigned)iz & 255u;
    const unsigned bz1 = (unsigned)(iz + 1) & 255u;

    const float v000 = vol[bx0 | by0 | bz0];
    const float v001 = vol[bx0 | by0 | bz1];
    const float v010 = vol[bx0 | by1 | bz0];
    const float v011 = vol[bx0 | by1 | bz1];
    const float v100 = vol[bx1 | by0 | bz0];
    const float v101 = vol[bx1 | by0 | bz1];
    const float v110 = vol[bx1 | by1 | bz0];
    const float v111 = vol[bx1 | by1 | bz1];

    const float wx0 = (1.0f - wx) * mx0, wx1 = wx * mx1;
    const float wy0 = (1.0f - wy) * my0, wy1 = wy * my1;
    const float wz0 = (1.0f - wz) * mz0, wz1 = wz * mz1;

    const float c00 = v000 * wz0 + v001 * wz1;
    const float c01 = v010 * wz0 + v011 * wz1;
    const float c10 = v100 * wz0 + v101 * wz1;
    const float c11 = v110 * wz0 + v111 * wz1;
    const float c0  = c00 * wy0 + c01 * wy1;
    const float c1  = c10 * wy0 + c11 * wy1;
    return c0 * wx0 + c1 * wx1;
}

// Block = 256 threads = 4 waves. Each block owns one 8x8 pixel tile; wave s
// integrates samples [64s, 64s+64). Lane l -> pixel (du=l&7, dv=l>>3).
// Grid = 2 images * 1024 tiles = 2048 blocks -> 8192 waves = 32 waves/CU.
__global__ __launch_bounds__(256, 8) void drr_main(const float* __restrict__ vol,
                                                   const float* __restrict__ batch,
                                                   float* __restrict__ raw,
                                                   unsigned* __restrict__ mm) {
    const int tid  = threadIdx.x;
    const int lane = tid & 63;
    const int seg  = tid >> 6;

    const int tile = blockIdx.x;
    const int b    = tile >> 10;          // 1024 tiles per image
    const int ti   = tile & 1023;
    const int u    = ((ti & 31) << 3) + (lane & 7);
    const int v    = ((ti >> 5) << 3) + (lane >> 3);

    // Pose (uniform per image).
    const float a  = batch[b * 6 + 0];
    const float be = batch[b * 6 + 1];
    const float g  = batch[b * 6 + 2];
    const float tx = batch[b * 6 + 3];
    const float ty = batch[b * 6 + 4];
    const float tz = batch[b * 6 + 5];

    float sa, ca, sb, cb, sg, cg;
    sincosf(a, &sa, &ca);
    sincosf(be, &sb, &cb);
    sincosf(g, &sg, &cg);

    // R = Rz(a) @ Ry(b) @ Rx(g)
    const float R00 = ca * cb;
    const float R01 = ca * sb * sg - sa * cg;
    const float R02 = sa * sg + ca * sb * cg;
    const float R10 = sa * cb;
    const float R11 = ca * cg + sa * sb * sg;
    const float R12 = sa * sb * cg - ca * sg;
    const float R20 = -sb;
    const float R21 = cb * sg;
    const float R22 = cb * cg;

    const float isox = 128.0f + tx, isoy = 128.0f + ty, isoz = 128.0f + tz;
    const float srcx = isox + kSAD * R02;
    const float srcy = isoy + kSAD * R12;
    const float srcz = isoz + kSAD * R22;

    const float uu = u * kPX - kPIERCE;
    const float vv = v * kPX - kPIERCE;

    // ray = (det_c + uu*R[:,0] + vv*R[:,1]) - source ; det_c = iso - DAD*R[:,2]
    const float rx = uu * R00 + vv * R01 - (kSAD + kDAD) * R02;
    const float ry = uu * R10 + vv * R11 - (kSAD + kDAD) * R12;
    const float rz = uu * R20 + vv * R21 - (kSAD + kDAD) * R22;
    const float length = sqrtf(rx * rx + ry * ry + rz * rz);

    const float tstep = 1.0f / 255.0f;  // t = linspace(0,1,256)
    float sum0 = 0.0f, sum1 = 0.0f;
    const int k0 = seg << 6;
    #pragma unroll 4
    for (int k = k0; k < k0 + 64; k += 2) {
        const float s0 = tri_sample(vol, srcx, srcy, srcz, rx, ry, rz, (float)k * tstep);
        const float s1 = tri_sample(vol, srcx, srcy, srcz, rx, ry, rz, (float)(k + 1) * tstep);
        sum0 += s0;
        sum1 += s1;
    }

    __shared__ float part[4][64];
    part[seg][lane] = sum0 + sum1;
    __syncthreads();

    if (tid < 64) {
        const float s = part[0][lane] + part[1][lane] + part[2][lane] + part[3][lane];
        const float rawv = s * (length * (1.0f / 256.0f));
        raw[(b << 16) + (v << 8) + u] = rawv;

        float mn = rawv, mx = rawv;
        #pragma unroll
        for (int off = 32; off >= 1; off >>= 1) {
            mn = fminf(mn, __shfl_xor(mn, off));
            mx = fmaxf(mx, __shfl_xor(mx, off));
        }
        if (lane == 0) {
            atomicMin(&mm[2 * b + 0], __float_as_uint(mn));
            atomicMax(&mm[2 * b + 1], __float_as_uint(mx));
        }
    }
}

__global__ __launch_bounds__(256) void drr_norm(float* __restrict__ img,
                                                const unsigned* __restrict__ mm) {
    const int gid = blockIdx.x * 256 + threadIdx.x;
    const int b   = gid >> 16;
    const float mn  = __uint_as_float(mm[2 * b + 0]);
    const float mx  = __uint_as_float(mm[2 * b + 1]);
    const float inv = 1.0f / (mx - mn);
    img[gid] = 1.0f - (img[gid] - mn) * inv;
}

extern "C" void kernel_launch(void* const* d_in, const int* in_sizes, int n_in,
                              void* d_out, int out_size, void* d_ws, size_t ws_size,
                              hipStream_t stream) {
    const float* vol   = (const float*)d_in[0];
    const float* batch = (const float*)d_in[1];
    float* out         = (float*)d_out;
    unsigned* mm       = (unsigned*)d_ws;

    drr_init_mm<<<1, 64, 0, stream>>>(mm);
    drr_main<<<2048, 256, 0, stream>>>(vol, batch, out, mm);
    drr_norm<<<512, 256, 0, stream>>>(out, mm);
}

// Round 4
// 108.782 us; speedup vs baseline: 7.6607x; 5.1128x over previous
//
#include <hip/hip_runtime.h>

// DRR ray-casting for MI355X — round 4 (= round 3 resubmitted; container died
// before benching r3).
// r2 was L1-line-request bound: (a) ~75% of samples are outside the volume but
// still issued 8 wrapped gathers each; (b) lane dim (u->x) is the 256KB-stride
// axis so a wave's 64 lanes touch ~64 distinct lines per load instruction.
// r3/r4: per-ray slab-test sample window + x-fastest transposed volume in d_ws.

static __device__ __constant__ float kPX     = 1.6875f;
static __device__ __constant__ float kPIERCE = 216.0f;
static __device__ __constant__ float kSAD    = 742.5f;
static __device__ __constant__ float kDAD    = 517.15f;

#define VOL_BYTES (256u * 256u * 256u * 4u)

__global__ void drr_init_mm(unsigned* mm) {
    int i = threadIdx.x;
    if (i < 4) mm[i] = (i & 1) ? 0u : 0x7F800000u;  // max<-0, min<-+inf
}

// Transpose vol[x][y][z] -> volt[z][y][x] (x becomes fastest axis).
// Block = 256 threads, one 64x64 (x,z) tile at fixed y. LDS pad 65 -> no bank
// conflicts on the column read (65 mod 32 = 1).
__global__ __launch_bounds__(256) void drr_transpose(const float* __restrict__ vol,
                                                     float* __restrict__ volt) {
    __shared__ float tile[64][65];
    const int bid  = blockIdx.x;
    const int y    = bid >> 4;
    const int t4   = bid & 15;
    const int x0   = (t4 & 3) << 6;
    const int z0   = (t4 >> 2) << 6;
    const int lane = threadIdx.x & 63;
    const int row4 = threadIdx.x >> 6;  // 0..3

    #pragma unroll
    for (int i = 0; i < 16; ++i) {
        const int xr = (i << 2) + row4;
        tile[xr][lane] = vol[((x0 + xr) << 16) | (y << 8) | (z0 + lane)];
    }
    __syncthreads();
    #pragma unroll
    for (int i = 0; i < 16; ++i) {
        const int zr = (i << 2) + row4;
        volt[((z0 + zr) << 16) | (y << 8) | (x0 + lane)] = tile[lane][zr];
    }
}

// One trilinear sample at parameter t. XFAST: volt[z][y][x] layout.
template <bool XFAST>
__device__ __forceinline__ float tri_sample(const float* __restrict__ vol,
                                            float srcx, float srcy, float srcz,
                                            float rx, float ry, float rz, float t) {
    const float px = fmaf(t, rx, srcx);
    const float py = fmaf(t, ry, srcy);
    const float pz = fmaf(t, rz, srcz);

    const float fx = floorf(px), fy = floorf(py), fz = floorf(pz);
    const int ix = (int)fx, iy = (int)fy, iz = (int)fz;
    const float wx = px - fx, wy = py - fy, wz = pz - fz;

    const float mx0 = ((unsigned)ix       < 256u) ? 1.0f : 0.0f;
    const float mx1 = ((unsigned)(ix + 1) < 256u) ? 1.0f : 0.0f;
    const float my0 = ((unsigned)iy       < 256u) ? 1.0f : 0.0f;
    const float my1 = ((unsigned)(iy + 1) < 256u) ? 1.0f : 0.0f;
    const float mz0 = ((unsigned)iz       < 256u) ? 1.0f : 0.0f;
    const float mz1 = ((unsigned)(iz + 1) < 256u) ? 1.0f : 0.0f;

    const unsigned ux0 = (unsigned)ix & 255u, ux1 = (unsigned)(ix + 1) & 255u;
    const unsigned uy0 = (unsigned)iy & 255u, uy1 = (unsigned)(iy + 1) & 255u;
    const unsigned uz0 = (unsigned)iz & 255u, uz1 = (unsigned)(iz + 1) & 255u;

    unsigned X0, X1, Y0, Y1, Z0, Z1;
    if (XFAST) {  // volt[z][y][x]
        X0 = ux0;       X1 = ux1;
        Y0 = uy0 << 8;  Y1 = uy1 << 8;
        Z0 = uz0 << 16; Z1 = uz1 << 16;
    } else {      // vol[x][y][z]
        X0 = ux0 << 16; X1 = ux1 << 16;
        Y0 = uy0 << 8;  Y1 = uy1 << 8;
        Z0 = uz0;       Z1 = uz1;
    }

    const float v000 = vol[X0 | Y0 | Z0];
    const float v001 = vol[X0 | Y0 | Z1];
    const float v010 = vol[X0 | Y1 | Z0];
    const float v011 = vol[X0 | Y1 | Z1];
    const float v100 = vol[X1 | Y0 | Z0];
    const float v101 = vol[X1 | Y0 | Z1];
    const float v110 = vol[X1 | Y1 | Z0];
    const float v111 = vol[X1 | Y1 | Z1];

    const float wx0 = (1.0f - wx) * mx0, wx1 = wx * mx1;
    const float wy0 = (1.0f - wy) * my0, wy1 = wy * my1;
    const float wz0 = (1.0f - wz) * mz0, wz1 = wz * mz1;

    const float c00 = v000 * wz0 + v001 * wz1;
    const float c01 = v010 * wz0 + v011 * wz1;
    const float c10 = v100 * wz0 + v101 * wz1;
    const float c11 = v110 * wz0 + v111 * wz1;
    const float c0  = c00 * wy0 + c01 * wy1;
    const float c1  = c10 * wy0 + c11 * wy1;
    return c0 * wx0 + c1 * wx1;
}

// Per-dimension slab: tighten [tlo, thi] to where s + t*r is in [-2, 258].
// Slack is harmless (masks make edge samples exact); never excludes a nonzero
// sample.
__device__ __forceinline__ void slab(float s, float r, float& tlo, float& thi) {
    if (fabsf(r) > 1e-8f) {
        const float inv = 1.0f / r;
        const float ta  = (-2.0f - s) * inv;
        const float tb  = (258.0f - s) * inv;
        tlo = fmaxf(tlo, fminf(ta, tb));
        thi = fminf(thi, fmaxf(ta, tb));
    } else if (s < -2.0f || s > 258.0f) {
        tlo = 2.0f; thi = -1.0f;  // empty
    }
}

// Block = 256 threads = 4 waves; one 8x8 pixel tile per block. Wave `seg`
// handles samples k = k_lo+seg, k_lo+seg+4, ... within the per-ray window.
template <bool XFAST>
__global__ __launch_bounds__(256, 8) void drr_main(const float* __restrict__ vol,
                                                   const float* __restrict__ batch,
                                                   float* __restrict__ raw,
                                                   unsigned* __restrict__ mm) {
    const int tid  = threadIdx.x;
    const int lane = tid & 63;
    const int seg  = tid >> 6;

    const int tile = blockIdx.x;
    const int b    = tile >> 10;
    const int ti   = tile & 1023;
    const int u    = ((ti & 31) << 3) + (lane & 7);
    const int v    = ((ti >> 5) << 3) + (lane >> 3);

    const float a  = batch[b * 6 + 0];
    const float be = batch[b * 6 + 1];
    const float g  = batch[b * 6 + 2];
    const float tx = batch[b * 6 + 3];
    const float ty = batch[b * 6 + 4];
    const float tz = batch[b * 6 + 5];

    float sa, ca, sb, cb, sg, cg;
    sincosf(a, &sa, &ca);
    sincosf(be, &sb, &cb);
    sincosf(g, &sg, &cg);

    const float R00 = ca * cb;
    const float R01 = ca * sb * sg - sa * cg;
    const float R02 = sa * sg + ca * sb * cg;
    const float R10 = sa * cb;
    const float R11 = ca * cg + sa * sb * sg;
    const float R12 = sa * sb * cg - ca * sg;
    const float R20 = -sb;
    const float R21 = cb * sg;
    const float R22 = cb * cg;

    const float srcx = 128.0f + tx + kSAD * R02;
    const float srcy = 128.0f + ty + kSAD * R12;
    const float srcz = 128.0f + tz + kSAD * R22;

    const float uu = u * kPX - kPIERCE;
    const float vv = v * kPX - kPIERCE;

    const float rx = uu * R00 + vv * R01 - (kSAD + kDAD) * R02;
    const float ry = uu * R10 + vv * R11 - (kSAD + kDAD) * R12;
    const float rz = uu * R20 + vv * R21 - (kSAD + kDAD) * R22;
    const float length = sqrtf(rx * rx + ry * ry + rz * rz);

    // Per-ray sample window via slab test (t in [0,1], k = t*255).
    float tlo = 0.0f, thi = 1.0f;
    slab(srcx, rx, tlo, thi);
    slab(srcy, ry, tlo, thi);
    slab(srcz, rz, tlo, thi);
    int k_lo = 0, k_hi = -1;
    if (thi >= tlo) {
        k_lo = max(0,   (int)floorf(tlo * 255.0f));
        k_hi = min(255, (int)ceilf(thi * 255.0f));
    }

    const float tstep = 1.0f / 255.0f;
    float sum = 0.0f;
    #pragma unroll 2
    for (int k = k_lo + seg; k <= k_hi; k += 4) {
        sum += tri_sample<XFAST>(vol, srcx, srcy, srcz, rx, ry, rz, (float)k * tstep);
    }

    __shared__ float part[4][64];
    part[seg][lane] = sum;
    __syncthreads();

    if (tid < 64) {
        const float s = part[0][lane] + part[1][lane] + part[2][lane] + part[3][lane];
        const float rawv = s * (length * (1.0f / 256.0f));
        raw[(b << 16) + (v << 8) + u] = rawv;

        float mn = rawv, mx = rawv;
        #pragma unroll
        for (int off = 32; off >= 1; off >>= 1) {
            mn = fminf(mn, __shfl_xor(mn, off));
            mx = fmaxf(mx, __shfl_xor(mx, off));
        }
        if (lane == 0) {
            atomicMin(&mm[2 * b + 0], __float_as_uint(mn));
            atomicMax(&mm[2 * b + 1], __float_as_uint(mx));
        }
    }
}

__global__ __launch_bounds__(256) void drr_norm(float* __restrict__ img,
                                                const unsigned* __restrict__ mm) {
    const int gid = blockIdx.x * 256 + threadIdx.x;
    const int b   = gid >> 16;
    const float mn  = __uint_as_float(mm[2 * b + 0]);
    const float mx  = __uint_as_float(mm[2 * b + 1]);
    const float inv = 1.0f / (mx - mn);
    img[gid] = 1.0f - (img[gid] - mn) * inv;
}

extern "C" void kernel_launch(void* const* d_in, const int* in_sizes, int n_in,
                              void* d_out, int out_size, void* d_ws, size_t ws_size,
                              hipStream_t stream) {
    const float* vol   = (const float*)d_in[0];
    const float* batch = (const float*)d_in[1];
    float* out         = (float*)d_out;

    if (ws_size >= (size_t)VOL_BYTES + 16) {
        float*    volt = (float*)d_ws;
        unsigned* mm   = (unsigned*)((char*)d_ws + VOL_BYTES);
        drr_init_mm<<<1, 64, 0, stream>>>(mm);
        drr_transpose<<<4096, 256, 0, stream>>>(vol, volt);
        drr_main<true><<<2048, 256, 0, stream>>>(volt, batch, out, mm);
        drr_norm<<<512, 256, 0, stream>>>(out, mm);
    } else {
        unsigned* mm = (unsigned*)d_ws;
        drr_init_mm<<<1, 64, 0, stream>>>(mm);
        drr_main<false><<<2048, 256, 0, stream>>>(vol, batch, out, mm);
        drr_norm<<<512, 256, 0, stream>>>(out, mm);
    }
}

// Round 5
// 105.634 us; speedup vs baseline: 7.8891x; 1.0298x over previous
//
#include <hip/hip_runtime.h>
#include <hip/hip_fp16.h>

// DRR ray-casting for MI355X — round 5.
// r4 was gather-instruction bound (~52 cyc per 64-lane gather, VALUBusy 18%).
// r5: fp16 x-pair packed volume vhp[z][y][i] = (v[x=i-1], v[x=i]) with zero
// padding at x=-1/256 -> 4 gathers per trilinear sample instead of 8, half
// the line width; 16x4 lane tile for fewer unique lines per gather.
// Fallback to the r4 f32-transpose path if ws is too small for the pair array.

static __device__ __constant__ float kPX     = 1.6875f;
static __device__ __constant__ float kPIERCE = 216.0f;
static __device__ __constant__ float kSAD    = 742.5f;
static __device__ __constant__ float kDAD    = 517.15f;

#define VOL_BYTES   (256u * 256u * 256u * 4u)
#define PAIR_R      258u
#define PAIR_ELEMS  (256u * 256u * PAIR_R)          // half2 elements
#define PAIR_BYTES  (PAIR_ELEMS * 4u)

__global__ void drr_init_mm(unsigned* mm) {
    int i = threadIdx.x;
    if (i < 4) mm[i] = (i & 1) ? 0u : 0x7F800000u;  // max<-0, min<-+inf
}

// ---------------- pack path: vol[x][y][z] -> vhp[z][y][i] (half2 pairs) -----
// Block: fixed y; 64x64 (x,z) tile. tile[xr][zr] holds x = x0-1+xr (65 rows).
__global__ __launch_bounds__(256) void drr_pack(const float* __restrict__ vol,
                                                __half2* __restrict__ vhp) {
    __shared__ float tile[65][65];
    const int bid  = blockIdx.x;
    const int y    = bid >> 4;
    const int t4   = bid & 15;
    const int x0   = (t4 & 3) << 6;
    const int z0   = (t4 >> 2) << 6;
    const int lane = threadIdx.x & 63;
    const int row4 = threadIdx.x >> 6;  // 0..3

    for (int r = row4; r < 65; r += 4) {
        const int x = x0 - 1 + r;
        tile[r][lane] = (x >= 0) ? vol[(x << 16) | (y << 8) | (z0 + lane)] : 0.0f;
    }
    __syncthreads();

    // i = x0 + lane in [x0, x0+64): pair (x=i-1, x=i) = (tile[lane], tile[lane+1])
    for (int r = row4; r < 64; r += 4) {
        const int z = z0 + r;
        const unsigned base = (unsigned)((z << 8) | y) * PAIR_R;
        vhp[base + x0 + lane] =
            __halves2half2(__float2half(tile[lane][r]), __float2half(tile[lane + 1][r]));
    }
    // entries i=256 (pair (vol[255], 0)) and i=257 (0,0), written by x0=192 blocks
    if ((t4 & 3) == 3) {
        for (int r = row4; r < 64; r += 4) {
            const int z = z0 + r;
            const unsigned base = (unsigned)((z << 8) | y) * PAIR_R;
            if (lane == 0) {
                vhp[base + 256] = __halves2half2(__float2half(tile[64][r]), __float2half(0.0f));
                vhp[base + 257] = __halves2half2(__float2half(0.0f), __float2half(0.0f));
            }
        }
    }
}

// Per-dimension slab: tighten [tlo, thi] to where s + t*r is in [lo, hi].
__device__ __forceinline__ void slab(float s, float r, float lo, float hi,
                                     float& tlo, float& thi) {
    if (fabsf(r) > 1e-8f) {
        const float inv = 1.0f / r;
        const float ta  = (lo - s) * inv;
        const float tb  = (hi - s) * inv;
        tlo = fmaxf(tlo, fminf(ta, tb));
        thi = fminf(thi, fmaxf(ta, tb));
    } else if (s < lo || s > hi) {
        tlo = 2.0f; thi = -1.0f;  // empty
    }
}

// One trilinear sample from the packed pair volume. 4 half2 gathers.
__device__ __forceinline__ float tri_sample_pk(const __half2* __restrict__ vhp,
                                               float srcx, float srcy, float srcz,
                                               float rx, float ry, float rz, float t) {
    const float px = fmaf(t, rx, srcx);
    const float py = fmaf(t, ry, srcy);
    const float pz = fmaf(t, rz, srcz);

    const float fx = floorf(px), fy = floorf(py), fz = floorf(pz);
    const int ix = (int)fx, iy = (int)fy, iz = (int)fz;
    const float wx = px - fx, wy = py - fy, wz = pz - fz;

    // masks (clamped/garbage loads are always multiplied by zero weight)
    const float mx0 = ((unsigned)ix       < 256u) ? 1.0f : 0.0f;
    const float mx1 = ((unsigned)(ix + 1) < 256u) ? 1.0f : 0.0f;
    const float my0 = ((unsigned)iy       < 256u) ? 1.0f : 0.0f;
    const float my1 = ((unsigned)(iy + 1) < 256u) ? 1.0f : 0.0f;
    const float mz0 = ((unsigned)iz       < 256u) ? 1.0f : 0.0f;
    const float mz1 = ((unsigned)(iz + 1) < 256u) ? 1.0f : 0.0f;

    const int i = min(max(ix + 1, 0), 257);
    const unsigned uy0 = (unsigned)iy & 255u, uy1 = (unsigned)(iy + 1) & 255u;
    const unsigned uz0 = (unsigned)iz & 255u, uz1 = (unsigned)(iz + 1) & 255u;

    // idx = (uz*256 + uy)*258 + i = uz*66048 + uy*258 + i
    const unsigned zt0 = (uz0 << 16) + (uz0 << 9);
    const unsigned zt1 = (uz1 << 16) + (uz1 << 9);
    const unsigned yt0 = (uy0 << 8) + (uy0 << 1);
    const unsigned yt1 = (uy1 << 8) + (uy1 << 1);

    const __half2 q00 = vhp[zt0 + yt0 + i];  // (v000, v100)
    const __half2 q01 = vhp[zt1 + yt0 + i];  // (v001, v101)
    const __half2 q10 = vhp[zt0 + yt1 + i];  // (v010, v110)
    const __half2 q11 = vhp[zt1 + yt1 + i];  // (v011, v111)

    const float wx0 = (1.0f - wx) * mx0, wx1 = wx * mx1;
    const float wy0 = (1.0f - wy) * my0, wy1 = wy * my1;
    const float wz0 = (1.0f - wz) * mz0, wz1 = wz * mz1;

    // x-lerp inside each pair
    const float a00 = __low2float(q00) * wx0 + __high2float(q00) * wx1;
    const float a01 = __low2float(q01) * wx0 + __high2float(q01) * wx1;
    const float a10 = __low2float(q10) * wx0 + __high2float(q10) * wx1;
    const float a11 = __low2float(q11) * wx0 + __high2float(q11) * wx1;

    return (a00 * wz0 + a01 * wz1) * wy0 + (a10 * wz0 + a11 * wz1) * wy1;
}

// Shared per-ray setup: returns geometry + k-window.
struct RayCfg {
    float sx, sy, sz, rx, ry, rz, length;
    int k_lo, k_hi;
};

__device__ __forceinline__ RayCfg ray_setup(const float* __restrict__ batch,
                                            int b, int u, int v) {
    const float a  = batch[b * 6 + 0];
    const float be = batch[b * 6 + 1];
    const float g  = batch[b * 6 + 2];
    const float tx = batch[b * 6 + 3];
    const float ty = batch[b * 6 + 4];
    const float tz = batch[b * 6 + 5];

    float sa, ca, sb, cb, sg, cg;
    sincosf(a, &sa, &ca);
    sincosf(be, &sb, &cb);
    sincosf(g, &sg, &cg);

    const float R00 = ca * cb;
    const float R01 = ca * sb * sg - sa * cg;
    const float R02 = sa * sg + ca * sb * cg;
    const float R10 = sa * cb;
    const float R11 = ca * cg + sa * sb * sg;
    const float R12 = sa * sb * cg - ca * sg;
    const float R20 = -sb;
    const float R21 = cb * sg;
    const float R22 = cb * cg;

    RayCfg c;
    c.sx = 128.0f + tx + kSAD * R02;
    c.sy = 128.0f + ty + kSAD * R12;
    c.sz = 128.0f + tz + kSAD * R22;

    const float uu = u * kPX - kPIERCE;
    const float vv = v * kPX - kPIERCE;
    c.rx = uu * R00 + vv * R01 - (kSAD + kDAD) * R02;
    c.ry = uu * R10 + vv * R11 - (kSAD + kDAD) * R12;
    c.rz = uu * R20 + vv * R21 - (kSAD + kDAD) * R22;
    c.length = sqrtf(c.rx * c.rx + c.ry * c.ry + c.rz * c.rz);

    // Samples with any coord outside [-1, 256] contribute exactly 0.
    float tlo = 0.0f, thi = 1.0f;
    slab(c.sx, c.rx, -1.02f, 256.02f, tlo, thi);
    slab(c.sy, c.ry, -1.02f, 256.02f, tlo, thi);
    slab(c.sz, c.rz, -1.02f, 256.02f, tlo, thi);
    c.k_lo = 0; c.k_hi = -1;
    if (thi >= tlo) {
        c.k_lo = max(0,   (int)ceilf(tlo * 255.0f - 1e-3f));
        c.k_hi = min(255, (int)floorf(thi * 255.0f + 1e-3f));
    }
    return c;
}

// Block = 256 threads = 4 waves; one 16x4 pixel tile per wave-lane-map; the
// block's 4 waves split the sample range with stride 4 (compact L1 footprint).
__global__ __launch_bounds__(256, 8) void drr_main_pk(const __half2* __restrict__ vhp,
                                                      const float* __restrict__ batch,
                                                      float* __restrict__ raw,
                                                      unsigned* __restrict__ mm) {
    const int tid  = threadIdx.x;
    const int lane = tid & 63;
    const int seg  = tid >> 6;

    const int tile = blockIdx.x;
    const int b    = tile >> 10;
    const int ti   = tile & 1023;
    const int u    = ((ti & 15) << 4) + (lane & 15);   // 16 u-pixels
    const int v    = ((ti >> 4) << 2) + (lane >> 4);   // 4 v-rows

    const RayCfg c = ray_setup(batch, b, u, v);

    const float tstep = 1.0f / 255.0f;
    float sum = 0.0f;
    #pragma unroll 2
    for (int k = c.k_lo + seg; k <= c.k_hi; k += 4) {
        sum += tri_sample_pk(vhp, c.sx, c.sy, c.sz, c.rx, c.ry, c.rz, (float)k * tstep);
    }

    __shared__ float part[4][64];
    part[seg][lane] = sum;
    __syncthreads();

    if (tid < 64) {
        const float s = part[0][lane] + part[1][lane] + part[2][lane] + part[3][lane];
        const float rawv = s * (c.length * (1.0f / 256.0f));
        raw[(b << 16) + (v << 8) + u] = rawv;

        float mn = rawv, mx = rawv;
        #pragma unroll
        for (int off = 32; off >= 1; off >>= 1) {
            mn = fminf(mn, __shfl_xor(mn, off));
            mx = fmaxf(mx, __shfl_xor(mx, off));
        }
        if (lane == 0) {
            atomicMin(&mm[2 * b + 0], __float_as_uint(mn));
            atomicMax(&mm[2 * b + 1], __float_as_uint(mx));
        }
    }
}

// ---------------- fallback path (r4, proven): f32 transposed volume ---------
__global__ __launch_bounds__(256) void drr_transpose(const float* __restrict__ vol,
                                                     float* __restrict__ volt) {
    __shared__ float tile[64][65];
    const int bid  = blockIdx.x;
    const int y    = bid >> 4;
    const int t4   = bid & 15;
    const int x0   = (t4 & 3) << 6;
    const int z0   = (t4 >> 2) << 6;
    const int lane = threadIdx.x & 63;
    const int row4 = threadIdx.x >> 6;

    #pragma unroll
    for (int i = 0; i < 16; ++i) {
        const int xr = (i << 2) + row4;
        tile[xr][lane] = vol[((x0 + xr) << 16) | (y << 8) | (z0 + lane)];
    }
    __syncthreads();
    #pragma unroll
    for (int i = 0; i < 16; ++i) {
        const int zr = (i << 2) + row4;
        volt[((z0 + zr) << 16) | (y << 8) | (x0 + lane)] = tile[lane][zr];
    }
}

__device__ __forceinline__ float tri_sample_f32(const float* __restrict__ vol,
                                                float srcx, float srcy, float srcz,
                                                float rx, float ry, float rz, float t) {
    const float px = fmaf(t, rx, srcx);
    const float py = fmaf(t, ry, srcy);
    const float pz = fmaf(t, rz, srcz);
    const float fx = floorf(px), fy = floorf(py), fz = floorf(pz);
    const int ix = (int)fx, iy = (int)fy, iz = (int)fz;
    const float wx = px - fx, wy = py - fy, wz = pz - fz;
    const float mx0 = ((unsigned)ix       < 256u) ? 1.0f : 0.0f;
    const float mx1 = ((unsigned)(ix + 1) < 256u) ? 1.0f : 0.0f;
    const float my0 = ((unsigned)iy       < 256u) ? 1.0f : 0.0f;
    const float my1 = ((unsigned)(iy + 1) < 256u) ? 1.0f : 0.0f;
    const float mz0 = ((unsigned)iz       < 256u) ? 1.0f : 0.0f;
    const float mz1 = ((unsigned)(iz + 1) < 256u) ? 1.0f : 0.0f;
    const unsigned X0 = (unsigned)ix & 255u, X1 = (unsigned)(ix + 1) & 255u;
    const unsigned Y0 = ((unsigned)iy & 255u) << 8, Y1 = ((unsigned)(iy + 1) & 255u) << 8;
    const unsigned Z0 = ((unsigned)iz & 255u) << 16, Z1 = ((unsigned)(iz + 1) & 255u) << 16;
    const float v000 = vol[Z0 | Y0 | X0];
    const float v001 = vol[Z1 | Y0 | X0];
    const float v010 = vol[Z0 | Y1 | X0];
    const float v011 = vol[Z1 | Y1 | X0];
    const float v100 = vol[Z0 | Y0 | X1];
    const float v101 = vol[Z1 | Y0 | X1];
    const float v110 = vol[Z0 | Y1 | X1];
    const float v111 = vol[Z1 | Y1 | X1];
    const float wx0 = (1.0f - wx) * mx0, wx1 = wx * mx1;
    const float wy0 = (1.0f - wy) * my0, wy1 = wy * my1;
    const float wz0 = (1.0f - wz) * mz0, wz1 = wz * mz1;
    const float c00 = v000 * wz0 + v001 * wz1;
    const float c01 = v010 * wz0 + v011 * wz1;
    const float c10 = v100 * wz0 + v101 * wz1;
    const float c11 = v110 * wz0 + v111 * wz1;
    return (c00 * wy0 + c01 * wy1) * wx0 + (c10 * wy0 + c11 * wy1) * wx1;
}

__global__ __launch_bounds__(256, 8) void drr_main_f32(const float* __restrict__ volt,
                                                       const float* __restrict__ batch,
                                                       float* __restrict__ raw,
                                                       unsigned* __restrict__ mm) {
    const int tid  = threadIdx.x;
    const int lane = tid & 63;
    const int seg  = tid >> 6;
    const int tile = blockIdx.x;
    const int b    = tile >> 10;
    const int ti   = tile & 1023;
    const int u    = ((ti & 15) << 4) + (lane & 15);
    const int v    = ((ti >> 4) << 2) + (lane >> 4);

    const RayCfg c = ray_setup(batch, b, u, v);

    const float tstep = 1.0f / 255.0f;
    float sum = 0.0f;
    #pragma unroll 2
    for (int k = c.k_lo + seg; k <= c.k_hi; k += 4) {
        sum += tri_sample_f32(volt, c.sx, c.sy, c.sz, c.rx, c.ry, c.rz, (float)k * tstep);
    }

    __shared__ float part[4][64];
    part[seg][lane] = sum;
    __syncthreads();

    if (tid < 64) {
        const float s = part[0][lane] + part[1][lane] + part[2][lane] + part[3][lane];
        const float rawv = s * (c.length * (1.0f / 256.0f));
        raw[(b << 16) + (v << 8) + u] = rawv;
        float mn = rawv, mx = rawv;
        #pragma unroll
        for (int off = 32; off >= 1; off >>= 1) {
            mn = fminf(mn, __shfl_xor(mn, off));
            mx = fmaxf(mx, __shfl_xor(mx, off));
        }
        if (lane == 0) {
            atomicMin(&mm[2 * b + 0], __float_as_uint(mn));
            atomicMax(&mm[2 * b + 1], __float_as_uint(mx));
        }
    }
}

__global__ __launch_bounds__(256) void drr_norm(float* __restrict__ img,
                                                const unsigned* __restrict__ mm) {
    const int gid = blockIdx.x * 256 + threadIdx.x;
    const int b   = gid >> 16;
    const float mn  = __uint_as_float(mm[2 * b + 0]);
    const float mx  = __uint_as_float(mm[2 * b + 1]);
    const float inv = 1.0f / (mx - mn);
    img[gid] = 1.0f - (img[gid] - mn) * inv;
}

extern "C" void kernel_launch(void* const* d_in, const int* in_sizes, int n_in,
                              void* d_out, int out_size, void* d_ws, size_t ws_size,
                              hipStream_t stream) {
    const float* vol   = (const float*)d_in[0];
    const float* batch = (const float*)d_in[1];
    float* out         = (float*)d_out;

    if (ws_size >= (size_t)PAIR_BYTES + 16) {
        __half2*  vhp = (__half2*)d_ws;
        unsigned* mm  = (unsigned*)((char*)d_ws + PAIR_BYTES);
        drr_init_mm<<<1, 64, 0, stream>>>(mm);
        drr_pack<<<4096, 256, 0, stream>>>(vol, vhp);
        drr_main_pk<<<2048, 256, 0, stream>>>(vhp, batch, out, mm);
        drr_norm<<<512, 256, 0, stream>>>(out, mm);
    } else {
        float*    volt = (float*)d_ws;
        unsigned* mm   = (unsigned*)((char*)d_ws + VOL_BYTES);
        drr_init_mm<<<1, 64, 0, stream>>>(mm);
        drr_transpose<<<4096, 256, 0, stream>>>(vol, volt);
        drr_main_f32<<<2048, 256, 0, stream>>>(volt, batch, out, mm);
        drr_norm<<<512, 256, 0, stream>>>(out, mm);
    }
}

// Round 6
// 100.764 us; speedup vs baseline: 8.2703x; 1.0483x over previous
//
#include <hip/hip_runtime.h>
#include <hip/hip_fp16.h>

// DRR ray-casting for MI355X — round 6.
// r5 was L2/L3-latency bound: ~1300 cyc per 4-load iteration, VGPR=32 (no ILP),
// and the pack pre-pass cost ~35 us of the 105 us total.
// r6: (a) ILP-4 in the sample loop (manual 2-sample interleave + unroll 2,
// launch_bounds(256,4) so VGPR can reach ~128); (b) float4-vectorized pack
// with mm-init folded in.

static __device__ __constant__ float kPX     = 1.6875f;
static __device__ __constant__ float kPIERCE = 216.0f;
static __device__ __constant__ float kSAD    = 742.5f;
static __device__ __constant__ float kDAD    = 517.15f;

#define VOL_BYTES   (256u * 256u * 256u * 4u)
#define PAIR_R      258u
#define PAIR_ELEMS  (256u * 256u * PAIR_R)          // half2 elements
#define PAIR_BYTES  (PAIR_ELEMS * 4u)

__global__ void drr_init_mm(unsigned* mm) {
    int i = threadIdx.x;
    if (i < 4) mm[i] = (i & 1) ? 0u : 0x7F800000u;  // max<-0, min<-+inf
}

// ---------------- pack: vol[x][y][z] -> vhp[z][y][i] = (v[i-1], v[i]) fp16 ---
// Block: fixed y; 64x64 (x,z) tile; tile[r][z] holds x = x0-1+r (65 rows).
// Loads vectorized float4 (16 threads x 16B = one 256B row per pass-row).
__global__ __launch_bounds__(256) void drr_pack(const float* __restrict__ vol,
                                                __half2* __restrict__ vhp,
                                                unsigned* __restrict__ mm) {
    if (blockIdx.x == 0 && threadIdx.x < 4)
        mm[threadIdx.x] = (threadIdx.x & 1) ? 0u : 0x7F800000u;

    __shared__ float tile[65][65];
    const int bid  = blockIdx.x;
    const int y    = bid >> 4;
    const int t4   = bid & 15;
    const int x0   = (t4 & 3) << 6;
    const int z0   = (t4 >> 2) << 6;

    const int rr = threadIdx.x >> 4;   // 0..15 row within pass
    const int cc = threadIdx.x & 15;   // 0..15 float4 column
    #pragma unroll
    for (int base = 0; base < 80; base += 16) {
        const int r = base + rr;
        if (r < 65) {
            const int x = x0 - 1 + r;
            float4 f = make_float4(0.0f, 0.0f, 0.0f, 0.0f);
            if (x >= 0)
                f = *(const float4*)&vol[(x << 16) | (y << 8) | (z0 + (cc << 2))];
            tile[r][(cc << 2) + 0] = f.x;
            tile[r][(cc << 2) + 1] = f.y;
            tile[r][(cc << 2) + 2] = f.z;
            tile[r][(cc << 2) + 3] = f.w;
        }
    }
    __syncthreads();

    const int lane = threadIdx.x & 63;
    const int row4 = threadIdx.x >> 6;  // 0..3
    // i = x0 + lane: pair (x=i-1, x=i) = (tile[lane][r], tile[lane+1][r])
    for (int r = row4; r < 64; r += 4) {
        const int z = z0 + r;
        const unsigned base = (unsigned)((z << 8) | y) * PAIR_R;
        vhp[base + x0 + lane] =
            __halves2half2(__float2half(tile[lane][r]), __float2half(tile[lane + 1][r]));
    }
    // entries i=256 (pair (vol[255], 0)) and i=257 (0,0), from x0=192 blocks
    if ((t4 & 3) == 3) {
        for (int r = row4; r < 64; r += 4) {
            const int z = z0 + r;
            const unsigned base = (unsigned)((z << 8) | y) * PAIR_R;
            if (lane == 0) {
                vhp[base + 256] = __halves2half2(__float2half(tile[64][r]), __float2half(0.0f));
                vhp[base + 257] = __halves2half2(__float2half(0.0f), __float2half(0.0f));
            }
        }
    }
}

// Per-dimension slab: tighten [tlo, thi] to where s + t*r is in [lo, hi].
__device__ __forceinline__ void slab(float s, float r, float lo, float hi,
                                     float& tlo, float& thi) {
    if (fabsf(r) > 1e-8f) {
        const float inv = 1.0f / r;
        const float ta  = (lo - s) * inv;
        const float tb  = (hi - s) * inv;
        tlo = fmaxf(tlo, fminf(ta, tb));
        thi = fminf(thi, fmaxf(ta, tb));
    } else if (s < lo || s > hi) {
        tlo = 2.0f; thi = -1.0f;  // empty
    }
}

// One trilinear sample from the packed pair volume. 4 half2 gathers.
// Any sample with a coordinate outside [-1,256] contributes exactly 0 via the
// masks, so callers may evaluate k beyond the window safely.
__device__ __forceinline__ float tri_sample_pk(const __half2* __restrict__ vhp,
                                               float srcx, float srcy, float srcz,
                                               float rx, float ry, float rz, float t) {
    const float px = fmaf(t, rx, srcx);
    const float py = fmaf(t, ry, srcy);
    const float pz = fmaf(t, rz, srcz);

    const float fx = floorf(px), fy = floorf(py), fz = floorf(pz);
    const int ix = (int)fx, iy = (int)fy, iz = (int)fz;
    const float wx = px - fx, wy = py - fy, wz = pz - fz;

    const float mx0 = ((unsigned)ix       < 256u) ? 1.0f : 0.0f;
    const float mx1 = ((unsigned)(ix + 1) < 256u) ? 1.0f : 0.0f;
    const float my0 = ((unsigned)iy       < 256u) ? 1.0f : 0.0f;
    const float my1 = ((unsigned)(iy + 1) < 256u) ? 1.0f : 0.0f;
    const float mz0 = ((unsigned)iz       < 256u) ? 1.0f : 0.0f;
    const float mz1 = ((unsigned)(iz + 1) < 256u) ? 1.0f : 0.0f;

    const int i = min(max(ix + 1, 0), 257);
    const unsigned uy0 = (unsigned)iy & 255u, uy1 = (unsigned)(iy + 1) & 255u;
    const unsigned uz0 = (unsigned)iz & 255u, uz1 = (unsigned)(iz + 1) & 255u;

    // idx = (uz*256 + uy)*258 + i
    const unsigned zt0 = (uz0 << 16) + (uz0 << 9);
    const unsigned zt1 = (uz1 << 16) + (uz1 << 9);
    const unsigned yt0 = (uy0 << 8) + (uy0 << 1);
    const unsigned yt1 = (uy1 << 8) + (uy1 << 1);

    const __half2 q00 = vhp[zt0 + yt0 + i];  // (v000, v100)
    const __half2 q01 = vhp[zt1 + yt0 + i];  // (v001, v101)
    const __half2 q10 = vhp[zt0 + yt1 + i];  // (v010, v110)
    const __half2 q11 = vhp[zt1 + yt1 + i];  // (v011, v111)

    const float wx0 = (1.0f - wx) * mx0, wx1 = wx * mx1;
    const float wy0 = (1.0f - wy) * my0, wy1 = wy * my1;
    const float wz0 = (1.0f - wz) * mz0, wz1 = wz * mz1;

    const float a00 = __low2float(q00) * wx0 + __high2float(q00) * wx1;
    const float a01 = __low2float(q01) * wx0 + __high2float(q01) * wx1;
    const float a10 = __low2float(q10) * wx0 + __high2float(q10) * wx1;
    const float a11 = __low2float(q11) * wx0 + __high2float(q11) * wx1;

    return (a00 * wz0 + a01 * wz1) * wy0 + (a10 * wz0 + a11 * wz1) * wy1;
}

struct RayCfg {
    float sx, sy, sz, rx, ry, rz, length;
    int k_lo, k_hi;
};

__device__ __forceinline__ RayCfg ray_setup(const float* __restrict__ batch,
                                            int b, int u, int v) {
    const float a  = batch[b * 6 + 0];
    const float be = batch[b * 6 + 1];
    const float g  = batch[b * 6 + 2];
    const float tx = batch[b * 6 + 3];
    const float ty = batch[b * 6 + 4];
    const float tz = batch[b * 6 + 5];

    float sa, ca, sb, cb, sg, cg;
    sincosf(a, &sa, &ca);
    sincosf(be, &sb, &cb);
    sincosf(g, &sg, &cg);

    const float R00 = ca * cb;
    const float R01 = ca * sb * sg - sa * cg;
    const float R02 = sa * sg + ca * sb * cg;
    const float R10 = sa * cb;
    const float R11 = ca * cg + sa * sb * sg;
    const float R12 = sa * sb * cg - ca * sg;
    const float R20 = -sb;
    const float R21 = cb * sg;
    const float R22 = cb * cg;

    RayCfg c;
    c.sx = 128.0f + tx + kSAD * R02;
    c.sy = 128.0f + ty + kSAD * R12;
    c.sz = 128.0f + tz + kSAD * R22;

    const float uu = u * kPX - kPIERCE;
    const float vv = v * kPX - kPIERCE;
    c.rx = uu * R00 + vv * R01 - (kSAD + kDAD) * R02;
    c.ry = uu * R10 + vv * R11 - (kSAD + kDAD) * R12;
    c.rz = uu * R20 + vv * R21 - (kSAD + kDAD) * R22;
    c.length = sqrtf(c.rx * c.rx + c.ry * c.ry + c.rz * c.rz);

    float tlo = 0.0f, thi = 1.0f;
    slab(c.sx, c.rx, -1.02f, 256.02f, tlo, thi);
    slab(c.sy, c.ry, -1.02f, 256.02f, tlo, thi);
    slab(c.sz, c.rz, -1.02f, 256.02f, tlo, thi);
    c.k_lo = 0; c.k_hi = -1;
    if (thi >= tlo) {
        c.k_lo = max(0,   (int)ceilf(tlo * 255.0f - 1e-3f));
        c.k_hi = min(255, (int)floorf(thi * 255.0f + 1e-3f));
    }
    return c;
}

// Block = 256 threads = 4 waves; one 16x4 pixel tile; wave `seg` covers k
// residues {seg, seg+4} mod 8. ILP: 2 samples per iteration (k, k+4), both
// unconditional (out-of-window samples are exactly 0), + unroll 2 -> ~4
// independent 4-load batches in flight per lane.
__global__ __launch_bounds__(256, 4) void drr_main_pk(const __half2* __restrict__ vhp,
                                                      const float* __restrict__ batch,
                                                      float* __restrict__ raw,
                                                      unsigned* __restrict__ mm) {
    const int tid  = threadIdx.x;
    const int lane = tid & 63;
    const int seg  = tid >> 6;

    const int tile = blockIdx.x;
    const int b    = tile >> 10;
    const int ti   = tile & 1023;
    const int u    = ((ti & 15) << 4) + (lane & 15);   // 16 u-pixels
    const int v    = ((ti >> 4) << 2) + (lane >> 4);   // 4 v-rows

    const RayCfg c = ray_setup(batch, b, u, v);

    const float tstep = 1.0f / 255.0f;
    float s0 = 0.0f, s1 = 0.0f;
    #pragma unroll 2
    for (int k = c.k_lo + seg; k <= c.k_hi; k += 8) {
        s0 += tri_sample_pk(vhp, c.sx, c.sy, c.sz, c.rx, c.ry, c.rz, (float)k * tstep);
        s1 += tri_sample_pk(vhp, c.sx, c.sy, c.sz, c.rx, c.ry, c.rz, (float)(k + 4) * tstep);
    }

    __shared__ float part[4][64];
    part[seg][lane] = s0 + s1;
    __syncthreads();

    if (tid < 64) {
        const float s = part[0][lane] + part[1][lane] + part[2][lane] + part[3][lane];
        const float rawv = s * (c.length * (1.0f / 256.0f));
        raw[(b << 16) + (v << 8) + u] = rawv;

        float mn = rawv, mx = rawv;
        #pragma unroll
        for (int off = 32; off >= 1; off >>= 1) {
            mn = fminf(mn, __shfl_xor(mn, off));
            mx = fmaxf(mx, __shfl_xor(mx, off));
        }
        if (lane == 0) {
            atomicMin(&mm[2 * b + 0], __float_as_uint(mn));
            atomicMax(&mm[2 * b + 1], __float_as_uint(mx));
        }
    }
}

// ---------------- fallback (ws too small for pair array): r4 f32 path -------
__global__ __launch_bounds__(256) void drr_transpose(const float* __restrict__ vol,
                                                     float* __restrict__ volt) {
    __shared__ float tile[64][65];
    const int bid  = blockIdx.x;
    const int y    = bid >> 4;
    const int t4   = bid & 15;
    const int x0   = (t4 & 3) << 6;
    const int z0   = (t4 >> 2) << 6;
    const int lane = threadIdx.x & 63;
    const int row4 = threadIdx.x >> 6;

    #pragma unroll
    for (int i = 0; i < 16; ++i) {
        const int xr = (i << 2) + row4;
        tile[xr][lane] = vol[((x0 + xr) << 16) | (y << 8) | (z0 + lane)];
    }
    __syncthreads();
    #pragma unroll
    for (int i = 0; i < 16; ++i) {
        const int zr = (i << 2) + row4;
        volt[((z0 + zr) << 16) | (y << 8) | (x0 + lane)] = tile[lane][zr];
    }
}

__device__ __forceinline__ float tri_sample_f32(const float* __restrict__ vol,
                                                float srcx, float srcy, float srcz,
                                                float rx, float ry, float rz, float t) {
    const float px = fmaf(t, rx, srcx);
    const float py = fmaf(t, ry, srcy);
    const float pz = fmaf(t, rz, srcz);
    const float fx = floorf(px), fy = floorf(py), fz = floorf(pz);
    const int ix = (int)fx, iy = (int)fy, iz = (int)fz;
    const float wx = px - fx, wy = py - fy, wz = pz - fz;
    const float mx0 = ((unsigned)ix       < 256u) ? 1.0f : 0.0f;
    const float mx1 = ((unsigned)(ix + 1) < 256u) ? 1.0f : 0.0f;
    const float my0 = ((unsigned)iy       < 256u) ? 1.0f : 0.0f;
    const float my1 = ((unsigned)(iy + 1) < 256u) ? 1.0f : 0.0f;
    const float mz0 = ((unsigned)iz       < 256u) ? 1.0f : 0.0f;
    const float mz1 = ((unsigned)(iz + 1) < 256u) ? 1.0f : 0.0f;
    const unsigned X0 = (unsigned)ix & 255u, X1 = (unsigned)(ix + 1) & 255u;
    const unsigned Y0 = ((unsigned)iy & 255u) << 8, Y1 = ((unsigned)(iy + 1) & 255u) << 8;
    const unsigned Z0 = ((unsigned)iz & 255u) << 16, Z1 = ((unsigned)(iz + 1) & 255u) << 16;
    const float v000 = vol[Z0 | Y0 | X0];
    const float v001 = vol[Z1 | Y0 | X0];
    const float v010 = vol[Z0 | Y1 | X0];
    const float v011 = vol[Z1 | Y1 | X0];
    const float v100 = vol[Z0 | Y0 | X1];
    const float v101 = vol[Z1 | Y0 | X1];
    const float v110 = vol[Z0 | Y1 | X1];
    const float v111 = vol[Z1 | Y1 | X1];
    const float wx0 = (1.0f - wx) * mx0, wx1 = wx * mx1;
    const float wy0 = (1.0f - wy) * my0, wy1 = wy * my1;
    const float wz0 = (1.0f - wz) * mz0, wz1 = wz * mz1;
    const float c00 = v000 * wz0 + v001 * wz1;
    const float c01 = v010 * wz0 + v011 * wz1;
    const float c10 = v100 * wz0 + v101 * wz1;
    const float c11 = v110 * wz0 + v111 * wz1;
    return (c00 * wy0 + c01 * wy1) * wx0 + (c10 * wy0 + c11 * wy1) * wx1;
}

__global__ __launch_bounds__(256, 4) void drr_main_f32(const float* __restrict__ volt,
                                                       const float* __restrict__ batch,
                                                       float* __restrict__ raw,
                                                       unsigned* __restrict__ mm) {
    const int tid  = threadIdx.x;
    const int lane = tid & 63;
    const int seg  = tid >> 6;
    const int tile = blockIdx.x;
    const int b    = tile >> 10;
    const int ti   = tile & 1023;
    const int u    = ((ti & 15) << 4) + (lane & 15);
    const int v    = ((ti >> 4) << 2) + (lane >> 4);

    const RayCfg c = ray_setup(batch, b, u, v);

    const float tstep = 1.0f / 255.0f;
    float s0 = 0.0f, s1 = 0.0f;
    #pragma unroll 2
    for (int k = c.k_lo + seg; k <= c.k_hi; k += 8) {
        s0 += tri_sample_f32(volt, c.sx, c.sy, c.sz, c.rx, c.ry, c.rz, (float)k * tstep);
        s1 += tri_sample_f32(volt, c.sx, c.sy, c.sz, c.rx, c.ry, c.rz, (float)(k + 4) * tstep);
    }

    __shared__ float part[4][64];
    part[seg][lane] = s0 + s1;
    __syncthreads();

    if (tid < 64) {
        const float s = part[0][lane] + part[1][lane] + part[2][lane] + part[3][lane];
        const float rawv = s * (c.length * (1.0f / 256.0f));
        raw[(b << 16) + (v << 8) + u] = rawv;
        float mn = rawv, mx = rawv;
        #pragma unroll
        for (int off = 32; off >= 1; off >>= 1) {
            mn = fminf(mn, __shfl_xor(mn, off));
            mx = fmaxf(mx, __shfl_xor(mx, off));
        }
        if (lane == 0) {
            atomicMin(&mm[2 * b + 0], __float_as_uint(mn));
            atomicMax(&mm[2 * b + 1], __float_as_uint(mx));
        }
    }
}

__global__ __launch_bounds__(256) void drr_norm(float* __restrict__ img,
                                                const unsigned* __restrict__ mm) {
    const int gid = blockIdx.x * 256 + threadIdx.x;
    const int b   = gid >> 16;
    const float mn  = __uint_as_float(mm[2 * b + 0]);
    const float mx  = __uint_as_float(mm[2 * b + 1]);
    const float inv = 1.0f / (mx - mn);
    img[gid] = 1.0f - (img[gid] - mn) * inv;
}

extern "C" void kernel_launch(void* const* d_in, const int* in_sizes, int n_in,
                              void* d_out, int out_size, void* d_ws, size_t ws_size,
                              hipStream_t stream) {
    const float* vol   = (const float*)d_in[0];
    const float* batch = (const float*)d_in[1];
    float* out         = (float*)d_out;

    if (ws_size >= (size_t)PAIR_BYTES + 16) {
        __half2*  vhp = (__half2*)d_ws;
        unsigned* mm  = (unsigned*)((char*)d_ws + PAIR_BYTES);
        drr_pack<<<4096, 256, 0, stream>>>(vol, vhp, mm);
        drr_main_pk<<<2048, 256, 0, stream>>>(vhp, batch, out, mm);
        drr_norm<<<512, 256, 0, stream>>>(out, mm);
    } else {
        float*    volt = (float*)d_ws;
        unsigned* mm   = (unsigned*)((char*)d_ws + VOL_BYTES);
        drr_init_mm<<<1, 64, 0, stream>>>(mm);
        drr_transpose<<<4096, 256, 0, stream>>>(vol, volt);
        drr_main_f32<<<2048, 256, 0, stream>>>(volt, batch, out, mm);
        drr_norm<<<512, 256, 0, stream>>>(out, mm);
    }
}